// Round 10
// baseline (70.926 us; speedup 1.0000x reference)
//
#include <hip/hip_runtime.h>
#include <hip/hip_bf16.h>
#include <math.h>

// B=8, N=16384 (H=W=128), C=64, heads=1, d=64, SR=8 -> Nk=256.
// S = X @ (Wq K^T)/8 ; P = softmax(S) ; out = P @ (V Wp) + bp
// R10 algebra: softmax is invariant to per-query / per-key additive consts,
// so K/V projections fold into precomputed 64x64 weights:
//   WK2 = SC*(Wkv_K @ Wq^T), WV2 = Wkv_V @ Wp, u = SC*Wkv_K@bq,
//   bp2 = bp + bkv_V@Wp.   (SC = 0.125*log2e; bkv_K/bq const terms cancel.)
// Pipeline (4 launches): prep0 (weight transpose + WK2/WV2/u/bp2) ->
// conv_mfma (partials) -> ln_prep (sum+LN+ MT/Vp/sb via MFMA) -> attn_mfma.
// attn: 8 waves x 2 query tiles (R8 ILP x R9 TLP), 66KB LDS, 4 waves/SIMD.

#define B 8
#define N 16384
#define C 64
#define NK 256
#define HW 128

typedef unsigned short ushort_t;
typedef unsigned int uint_t;
typedef __attribute__((ext_vector_type(8))) short short8v;
typedef __attribute__((ext_vector_type(16))) float f32x16;

static __device__ inline ushort_t f2bf(float f) {
  __hip_bfloat16 h = __float2bfloat16(f);
  return *reinterpret_cast<ushort_t*>(&h);
}
// single-instruction packed convert: dst.lo = bf16(a), dst.hi = bf16(b)
static __device__ inline uint_t cvtpk(float a, float b) {
  uint_t r;
  asm("v_cvt_pk_bf16_f32 %0, %1, %2" : "=v"(r) : "v"(a), "v"(b));
  return r;
}
static __device__ inline short8v mk8(uint_t a, uint_t b, uint_t c, uint_t d) {
  union { int4 i; short8v s; } u;
  u.i = make_int4((int)a, (int)b, (int)c, (int)d);
  return u.s;
}
static __device__ inline float sum16(const f32x16 v) {
  float a = ((v[0] + v[1]) + (v[2] + v[3])) + ((v[4] + v[5]) + (v[6] + v[7]));
  float b = ((v[8] + v[9]) + (v[10] + v[11])) + ((v[12] + v[13]) + (v[14] + v[15]));
  return a + b;
}

// ---------------------------------------------------------------------------
// Kernel 1 (prep0): blocks [0,1024): sr_w -> Wf fragment layout.
// Blocks [1024,1040): WK2/WV2 (stored B-fragment-linear).  Block 1040: u, bp2.
__global__ __launch_bounds__(256) void prep0(
    const float* __restrict__ sr_w, const float* __restrict__ Wq,
    const float* __restrict__ Wkv, const float* __restrict__ bq,
    const float* __restrict__ Wp, const float* __restrict__ bkv,
    const float* __restrict__ bp, ushort_t* __restrict__ Wf,
    ushort_t* __restrict__ W2f, float* __restrict__ u,
    float* __restrict__ bp2) {
  const int bid = blockIdx.x;
  const int t = threadIdx.x;
  const float SC = 0.125f * 1.4426950408889634f;
  if (bid < 1024) {
    int idx = bid * 256 + t;      // 262144
    int o = idx >> 12;
    int r = idx & 4095;
    int c = r >> 6;
    int ki = (r >> 3) & 7;
    int kj = r & 7;
    int oh = o >> 5;
    int l = ((c >> 3) & 1) * 32 + (o & 31);
    int kk = kj * 4 + (c >> 4);
    int e = c & 7;
    Wf[(ki * 2 + oh) * 16384 + kk * 512 + l * 8 + e] = f2bf(sr_w[idx]);
  } else if (bid < 1040) {
    const int eb = bid - 1024;
#pragma unroll
    for (int q = 0; q < 2; ++q) {
      int oidx = eb * 512 + t * 2 + q;   // [0,8192)
      int mat = oidx >> 12;
      int rem = oidx & 4095;
      int d = rem >> 6;
      int c = rem & 63;
      float s = 0.f;
      if (mat == 0) {
        const float* wk = Wkv + d * 128;
        const float* wq = Wq + c * 64;
#pragma unroll 16
        for (int e = 0; e < 64; ++e) s += wk[e] * wq[e];
        s *= SC;
      } else {
        const float* wk = Wkv + d * 128 + 64;
#pragma unroll 16
        for (int e = 0; e < 64; ++e) s += wk[e] * Wp[e * 64 + c];
      }
      // B-frag layout: chunk((mat*2 + c>>5)*4 + d>>4), l=((d>>3)&1)*32+(c&31)
      W2f[((mat * 2 + (c >> 5)) * 4 + (d >> 4)) * 512 +
          (((d >> 3) & 1) * 32 + (c & 31)) * 8 + (d & 7)] = f2bf(s);
    }
  } else {
    if (t < 64) {
      float s = 0.f;
      const float* wk = Wkv + t * 128;
#pragma unroll 16
      for (int e = 0; e < 64; ++e) s += wk[e] * bq[e];
      u[t] = s * SC;
    } else if (t < 128) {
      int c = t - 64;
      float s = bp[c];
#pragma unroll 16
      for (int e = 0; e < 64; ++e) s += bkv[64 + e] * Wp[e * 64 + c];
      bp2[c] = s;
    }
  }
}

// ---------------------------------------------------------------------------
// Kernel A: conv partial GEMM (unchanged).
__global__ __launch_bounds__(128) void conv_mfma(
    const float* __restrict__ x, const ushort_t* __restrict__ Wf,
    float* __restrict__ part) {
  const int t = threadIdx.x;
  const int bi = blockIdx.x;
  const int b = bi >> 6;
  const int pg = (bi >> 3) & 7;
  const int ki = bi & 7;
  const int oh = t >> 6;
  const int lane = t & 63;
  const int lo5 = lane & 31;
  const int hi = lane >> 5;

  const int P = pg * 32 + lo5;
  const int prow = P >> 4, pcol = P & 15;
  const float* rowbase =
      x + ((size_t)b * N + (prow * 8 + ki) * HW + pcol * 8) * C;
  const ushort_t* wbase = Wf + (ki * 2 + oh) * 16384 + lane * 8;

  f32x16 acc;
#pragma unroll
  for (int r = 0; r < 16; ++r) acc[r] = 0.f;

#pragma unroll
  for (int kk = 0; kk < 32; ++kk) {
    const int kj = kk >> 2;
    const int c0 = (kk & 3) * 16 + hi * 8;
    const float4* xp = reinterpret_cast<const float4*>(rowbase + kj * C + c0);
    float4 f0 = xp[0];
    float4 f1 = xp[1];
    short8v bfr = mk8(cvtpk(f0.x, f0.y), cvtpk(f0.z, f0.w), cvtpk(f1.x, f1.y),
                      cvtpk(f1.z, f1.w));
    short8v afr = *reinterpret_cast<const short8v*>(wbase + kk * 512);
    acc = __builtin_amdgcn_mfma_f32_32x32x16_bf16(afr, bfr, acc, 0, 0, 0);
  }

  float* dst = part + (size_t)bi * 2048 + oh * 1024 + lane * 16;
#pragma unroll
  for (int q = 0; q < 4; ++q) {
    *reinterpret_cast<float4*>(dst + 4 * q) =
        make_float4(acc[4 * q + 0], acc[4 * q + 1], acc[4 * q + 2],
                    acc[4 * q + 3]);
  }
}

// ---------------------------------------------------------------------------
// Kernel L (R10): sum ki-partials + bias + LayerNorm + MT/Vp/sb directly.
// Grid 64 = b(8) x pg(8); 256 thr = 4 waves. Wave (mat, n0) computes a
// 32x32 tile: MT (mat=0) = ns@WK2, Vp (mat=1) = ns@WV2; scatter to frag layout.
__global__ __launch_bounds__(256) void ln_prep(
    const float* __restrict__ part, const float* __restrict__ sr_b,
    const float* __restrict__ ln_g, const float* __restrict__ ln_b,
    const ushort_t* __restrict__ W2f, const float* __restrict__ u,
    ushort_t* __restrict__ MTf, ushort_t* __restrict__ VpTf,
    ushort_t* __restrict__ sbf) {
  __shared__ float convs[32 * 68];
  __shared__ float ns[32 * 68];   // stride 68: 16B-aligned rows, 4-way banks

  const int t = threadIdx.x;
  const int b = blockIdx.x >> 3;
  const int pg = blockIdx.x & 7;
  const size_t obase = (size_t)b * 16384;

  // ---- Phase A: sum 8 ki partials + conv bias ----
  {
    const int lane = t & 63;
    const int rhalf = (t >> 6) & 1;
    const int oh = t >> 7;
    float a[8];
#pragma unroll
    for (int r = 0; r < 8; ++r) a[r] = 0.f;
#pragma unroll
    for (int ki = 0; ki < 8; ++ki) {
      const float* src = part + ((size_t)(b * 64 + pg * 8 + ki)) * 2048 +
                         oh * 1024 + lane * 16 + rhalf * 8;
      float4 u0 = *reinterpret_cast<const float4*>(src + 0);
      float4 u1 = *reinterpret_cast<const float4*>(src + 4);
      a[0] += u0.x; a[1] += u0.y; a[2] += u0.z; a[3] += u0.w;
      a[4] += u1.x; a[5] += u1.y; a[6] += u1.z; a[7] += u1.w;
    }
    const int p = lane & 31;
#pragma unroll
    for (int r = 0; r < 8; ++r) {
      int reg = rhalf * 8 + r;
      int o = oh * 32 + (reg & 3) + 8 * (reg >> 2) + 4 * (lane >> 5);
      convs[p * 68 + o] = a[r] + sr_b[o];
    }
  }
  __syncthreads();
  // ---- Phase B: LayerNorm (4 waves x 8 rows) ----
  {
    const int lane = t & 63;
    const int w = t >> 6;
    float g = ln_g[lane], bb = ln_b[lane];
#pragma unroll
    for (int rr = 0; rr < 8; ++rr) {
      int p = w * 8 + rr;
      float v = convs[p * 68 + lane];
      float s = v, s2 = v * v;
#pragma unroll
      for (int mask = 1; mask < 64; mask <<= 1) {
        s += __shfl_xor(s, mask, 64);
        s2 += __shfl_xor(s2, mask, 64);
      }
      float mu = s * (1.f / 64.f);
      float var = s2 * (1.f / 64.f) - mu * mu;
      ns[p * 68 + lane] = (v - mu) * rsqrtf(var + 1e-5f) * g + bb;
    }
  }
  __syncthreads();
  // ---- Phase C: per-wave 32x32 GEMM tile ----
  {
    const int w = t >> 6;
    const int lane = t & 63;
    const int lo5 = lane & 31;
    const int hi = lane >> 5;
    const int mat = w >> 1;     // 0 = MT, 1 = Vp
    const int n0 = w & 1;       // column half

    f32x16 acc;
#pragma unroll
    for (int r = 0; r < 16; ++r) acc[r] = 0.f;
#pragma unroll
    for (int ks = 0; ks < 4; ++ks) {
      float4 f0 = *reinterpret_cast<const float4*>(&ns[lo5 * 68 + ks * 16 + hi * 8]);
      float4 f1 = *reinterpret_cast<const float4*>(&ns[lo5 * 68 + ks * 16 + hi * 8 + 4]);
      short8v A = mk8(cvtpk(f0.x, f0.y), cvtpk(f0.z, f0.w), cvtpk(f1.x, f1.y),
                      cvtpk(f1.z, f1.w));
      short8v Bw = *reinterpret_cast<const short8v*>(
          W2f + ((mat * 2 + n0) * 4 + ks) * 512 + lane * 8);
      acc = __builtin_amdgcn_mfma_f32_32x32x16_bf16(A, Bw, acc, 0, 0, 0);
    }
    const int c = n0 * 32 + lo5;
    if (mat == 0) {
#pragma unroll
      for (int r = 0; r < 16; ++r) {
        int jl = (r & 3) + 8 * (r >> 2) + 4 * hi;
        MTf[obase + (pg * 4 + (c >> 4)) * 512 +
            (((c >> 3) & 1) * 32 + jl) * 8 + (c & 7)] = f2bf(acc[r]);
      }
    } else {
#pragma unroll
      for (int r = 0; r < 16; ++r) {
        int jg = pg * 32 + (r & 3) + 8 * (r >> 2) + 4 * hi;
        VpTf[obase + (n0 * 16 + (jg >> 4)) * 512 +
             (((jg >> 3) & 1) * 32 + (c & 31)) * 8 + (jg & 7)] = f2bf(acc[r]);
      }
    }
    // ---- sb[j] = ns[j] . u  (SC folded into u) ----
    if (w == 0) {
      float s = 0.f;
      const float* ub = u + hi * 32;
#pragma unroll 8
      for (int dd = 0; dd < 32; ++dd) s += ns[lo5 * 68 + hi * 32 + dd] * ub[dd];
      s += __shfl_xor(s, 32, 64);
      if (hi == 0) sbf[b * NK + pg * 32 + lo5] = f2bf(s);
    }
  }
}

// ---------------------------------------------------------------------------
// Kernel B (R10): fused attention, 8 waves x 2 query tiles, 66KB LDS.
// Grid 256 = b(8) x qb(32); 512 thr; block = 512 queries; 2 blocks/CU
// = 16 waves/CU = 4 waves/SIMD, with 2x ILP per wave.
__global__ __launch_bounds__(512, 4) void attn_mfma(
    const float* __restrict__ x, const ushort_t* __restrict__ MTf,
    const ushort_t* __restrict__ VpTf, const ushort_t* __restrict__ sbf,
    const float* __restrict__ bp2, float* __restrict__ outp) {
  __shared__ ushort_t sMT[16384];
  __shared__ ushort_t sVT[16384];
  __shared__ ushort_t sSB[256];

  const int t = threadIdx.x;
  const int b = blockIdx.x >> 5;
  const int qb = blockIdx.x & 31;
  const int wave = t >> 6;
  const int lane = t & 63;
  const int lo5 = lane & 31;
  const int hi = lane >> 5;

  // ---- issue x loads FIRST (latency hides under staging + barrier) ----
  const int row0 = qb * 512 + wave * 64 + lo5;   // tile1 rows = row0 + 32
  const float4* xp0 =
      reinterpret_cast<const float4*>(x + ((size_t)b * N + row0) * 64);
  const float4* xp1 =
      reinterpret_cast<const float4*>(x + ((size_t)b * N + row0 + 32) * 64);
  float4 xf0[8], xf1[8];
#pragma unroll
  for (int ks = 0; ks < 4; ++ks) {
    xf0[2 * ks + 0] = xp0[ks * 4 + hi * 2 + 0];
    xf0[2 * ks + 1] = xp0[ks * 4 + hi * 2 + 1];
    xf1[2 * ks + 0] = xp1[ks * 4 + hi * 2 + 0];
    xf1[2 * ks + 1] = xp1[ks * 4 + hi * 2 + 1];
  }

  // ---- cooperative staging: MT + VpT + sb (512 threads) ----
  {
    const uint4* gm = reinterpret_cast<const uint4*>(MTf + (size_t)b * 16384);
    const uint4* gv = reinterpret_cast<const uint4*>(VpTf + (size_t)b * 16384);
    uint4* dm = reinterpret_cast<uint4*>(sMT);
    uint4* dv = reinterpret_cast<uint4*>(sVT);
#pragma unroll
    for (int i = 0; i < 4; ++i) {
      dm[t + i * 512] = gm[t + i * 512];
      dv[t + i * 512] = gv[t + i * 512];
    }
    if (t < 32)
      reinterpret_cast<uint4*>(sSB)[t] =
          reinterpret_cast<const uint4*>(sbf + b * NK)[t];
  }
  __syncthreads();

  // ---- pack X B-fragments for both tiles ----
  short8v bx0[4], bx1[4];
#pragma unroll
  for (int ks = 0; ks < 4; ++ks) {
    bx0[ks] = mk8(cvtpk(xf0[2 * ks].x, xf0[2 * ks].y),
                  cvtpk(xf0[2 * ks].z, xf0[2 * ks].w),
                  cvtpk(xf0[2 * ks + 1].x, xf0[2 * ks + 1].y),
                  cvtpk(xf0[2 * ks + 1].z, xf0[2 * ks + 1].w));
    bx1[ks] = mk8(cvtpk(xf1[2 * ks].x, xf1[2 * ks].y),
                  cvtpk(xf1[2 * ks].z, xf1[2 * ks].w),
                  cvtpk(xf1[2 * ks + 1].x, xf1[2 * ks + 1].y),
                  cvtpk(xf1[2 * ks + 1].z, xf1[2 * ks + 1].w));
  }

  f32x16 o0[2], o1[2];
#pragma unroll
  for (int ct = 0; ct < 2; ++ct)
#pragma unroll
    for (int r = 0; r < 16; ++r) { o0[ct][r] = 0.f; o1[ct][r] = 0.f; }
  float sum0 = 0.f, sum1 = 0.f;

#pragma unroll 2
  for (int kt = 0; kt < 8; ++kt) {
    // ---- QK^T for this 32-key tile, both query tiles ----
    f32x16 a0, a1;
#pragma unroll
    for (int r = 0; r < 16; ++r) { a0[r] = 0.f; a1[r] = 0.f; }
#pragma unroll
    for (int ks = 0; ks < 4; ++ks) {
      const short8v a =
          *reinterpret_cast<const short8v*>(&sMT[(kt * 4 + ks) * 512 + lane * 8]);
      a0 = __builtin_amdgcn_mfma_f32_32x32x16_bf16(a, bx0[ks], a0, 0, 0, 0);
      a1 = __builtin_amdgcn_mfma_f32_32x32x16_bf16(a, bx1[ks], a1, 0, 0, 0);
    }
    {
      ushort_t sv = sSB[kt * 32 + lo5];
      short8v a5 = mk8(hi ? 0u : (uint_t)sv, 0u, 0u, 0u);
      short8v b5 = mk8(hi ? 0u : 0x3F80u, 0u, 0u, 0u);
      a0 = __builtin_amdgcn_mfma_f32_32x32x16_bf16(a5, b5, a0, 0, 0, 0);
      a1 = __builtin_amdgcn_mfma_f32_32x32x16_bf16(a5, b5, a1, 0, 0, 0);
    }
    // ---- exp2 (no max-shift: logits small for this problem's scaling) ----
#pragma unroll
    for (int r = 0; r < 16; ++r) { a0[r] = exp2f(a0[r]); a1[r] = exp2f(a1[r]); }
    sum0 += sum16(a0);
    sum1 += sum16(a1);
    // ---- pack P, accumulate PV (va fragment shared across tiles) ----
#pragma unroll
    for (int h = 0; h < 2; ++h) {
      const int m0 = 2 * h;
      uint_t A0 = cvtpk(a0[4 * m0 + 0], a0[4 * m0 + 1]);
      uint_t B0 = cvtpk(a0[4 * m0 + 2], a0[4 * m0 + 3]);
      uint_t C0 = cvtpk(a0[4 * m0 + 4], a0[4 * m0 + 5]);
      uint_t D0 = cvtpk(a0[4 * m0 + 6], a0[4 * m0 + 7]);
      asm volatile("v_permlane32_swap_b32 %0, %1" : "+v"(A0), "+v"(C0));
      asm volatile("v_permlane32_swap_b32 %0, %1" : "+v"(B0), "+v"(D0));
      const short8v pb0 = mk8(A0, B0, C0, D0);
      uint_t A1 = cvtpk(a1[4 * m0 + 0], a1[4 * m0 + 1]);
      uint_t B1 = cvtpk(a1[4 * m0 + 2], a1[4 * m0 + 3]);
      uint_t C1 = cvtpk(a1[4 * m0 + 4], a1[4 * m0 + 5]);
      uint_t D1 = cvtpk(a1[4 * m0 + 6], a1[4 * m0 + 7]);
      asm volatile("v_permlane32_swap_b32 %0, %1" : "+v"(A1), "+v"(C1));
      asm volatile("v_permlane32_swap_b32 %0, %1" : "+v"(B1), "+v"(D1));
      const short8v pb1 = mk8(A1, B1, C1, D1);
#pragma unroll
      for (int ct = 0; ct < 2; ++ct) {
        const short8v va = *reinterpret_cast<const short8v*>(
            &sVT[(ct * 16 + kt * 2 + h) * 512 + lane * 8]);
        o0[ct] = __builtin_amdgcn_mfma_f32_32x32x16_bf16(va, pb0, o0[ct], 0, 0, 0);
        o1[ct] = __builtin_amdgcn_mfma_f32_32x32x16_bf16(va, pb1, o1[ct], 0, 0, 0);
      }
    }
  }

  sum0 += __shfl_xor(sum0, 32, 64);
  sum1 += __shfl_xor(sum1, 32, 64);
  const float linv0 = 1.f / sum0;
  const float linv1 = 1.f / sum1;

  // ---- epilogue (bp2 = bp + bkv_V@Wp) ----
  float* orow0 = outp + ((size_t)b * N + row0) * 64;
  float* orow1 = orow0 + 32 * 64;
#pragma unroll
  for (int ct = 0; ct < 2; ++ct) {
#pragma unroll
    for (int mm = 0; mm < 4; ++mm) {
      int c0 = ct * 32 + mm * 8 + hi * 4;
      float4 bpv = *reinterpret_cast<const float4*>(bp2 + c0);
      float4 r0, r1;
      r0.x = o0[ct][4 * mm + 0] * linv0 + bpv.x;
      r0.y = o0[ct][4 * mm + 1] * linv0 + bpv.y;
      r0.z = o0[ct][4 * mm + 2] * linv0 + bpv.z;
      r0.w = o0[ct][4 * mm + 3] * linv0 + bpv.w;
      *reinterpret_cast<float4*>(orow0 + c0) = r0;
      r1.x = o1[ct][4 * mm + 0] * linv1 + bpv.x;
      r1.y = o1[ct][4 * mm + 1] * linv1 + bpv.y;
      r1.z = o1[ct][4 * mm + 2] * linv1 + bpv.z;
      r1.w = o1[ct][4 * mm + 3] * linv1 + bpv.w;
      *reinterpret_cast<float4*>(orow1 + c0) = r1;
    }
  }
}

// ---------------------------------------------------------------------------
extern "C" void kernel_launch(void* const* d_in, const int* in_sizes, int n_in,
                              void* d_out, int out_size, void* d_ws,
                              size_t ws_size, hipStream_t stream) {
  const float* x    = (const float*)d_in[0];
  const float* Wq   = (const float*)d_in[3];
  const float* bq   = (const float*)d_in[4];
  const float* Wkv  = (const float*)d_in[5];
  const float* bkv  = (const float*)d_in[6];
  const float* sr_w = (const float*)d_in[7];
  const float* sr_b = (const float*)d_in[8];
  const float* ln_g = (const float*)d_in[9];
  const float* ln_b = (const float*)d_in[10];
  const float* Wp   = (const float*)d_in[11];
  const float* bp   = (const float*)d_in[12];
  float* outp = (float*)d_out;

  char* ws = (char*)d_ws;
  // [0, 512K)      Wf    bf16 conv weight fragments
  // [512K, 528K)   W2f   bf16 WK2/WV2 fragments (16KB)
  // [528K, +256)   u     fp32[64]
  // [528K+256,+512) bp2  fp32[64]
  // [1M, 5M)       part  fp32 conv partials
  // [5M, 5.25M)    MTf   [5.25M, 5.5M) VpTf   [5.5M, +4K) sbf
  ushort_t* Wf   = (ushort_t*)(ws);
  ushort_t* W2f  = (ushort_t*)(ws + (512 << 10));
  float*    u    = (float*)(ws + (528 << 10));
  float*    bp2  = (float*)(ws + (528 << 10) + 256);
  float*    part = (float*)(ws + (1024 << 10));
  ushort_t* MTf  = (ushort_t*)(ws + (5120 << 10));
  ushort_t* VpTf = (ushort_t*)(ws + (5376 << 10));
  ushort_t* sbf  = (ushort_t*)(ws + (5632 << 10));

  prep0<<<1041, 256, 0, stream>>>(sr_w, Wq, Wkv, bq, Wp, bkv, bp, Wf, W2f, u, bp2);
  conv_mfma<<<512, 128, 0, stream>>>(x, Wf, part);
  ln_prep<<<64, 256, 0, stream>>>(part, sr_b, ln_g, ln_b, W2f, u, MTf, VpTf, sbf);
  attn_mfma<<<256, 512, 0, stream>>>(x, MTf, VpTf, sbf, bp2, outp);
}

// Round 11
// 59.981 us; speedup vs baseline: 1.1825x; 1.1825x over previous
//
#include <hip/hip_runtime.h>
#include <hip/hip_bf16.h>
#include <math.h>

// B=8, N=16384 (H=W=128), C=64, heads=1, d=64, SR=8 -> Nk=256.
// S = X @ (Wq K^T)/8 ; P = softmax(S) ; out = P @ (V Wp) + bp
// R10 algebra kept: WK2 = SC*(Wkv_K @ Wq^T), WV2 = Wkv_V @ Wp, u = SC*Wkv_K@bq,
// bp2 = bp + bkv_V@Wp (softmax invariant to per-query/per-key additive consts).
// R11: attn re-balanced for occupancy. Only MT+sb staged in LDS (33KB);
// VpT read from global (L2-resident, 32KB/batch). 256-thr blocks, grid 1024
// -> 4 blocks/CU = 16 waves/CU = 4 waves/SIMD with 4 independent blocks/CU.
// (R10's 512-query blocks gave grid 256 = 1 block/CU = 2 waves/SIMD -> 48us.)

#define B 8
#define N 16384
#define C 64
#define NK 256
#define HW 128

typedef unsigned short ushort_t;
typedef unsigned int uint_t;
typedef __attribute__((ext_vector_type(8))) short short8v;
typedef __attribute__((ext_vector_type(16))) float f32x16;

static __device__ inline ushort_t f2bf(float f) {
  __hip_bfloat16 h = __float2bfloat16(f);
  return *reinterpret_cast<ushort_t*>(&h);
}
// single-instruction packed convert: dst.lo = bf16(a), dst.hi = bf16(b)
static __device__ inline uint_t cvtpk(float a, float b) {
  uint_t r;
  asm("v_cvt_pk_bf16_f32 %0, %1, %2" : "=v"(r) : "v"(a), "v"(b));
  return r;
}
static __device__ inline short8v mk8(uint_t a, uint_t b, uint_t c, uint_t d) {
  union { int4 i; short8v s; } u;
  u.i = make_int4((int)a, (int)b, (int)c, (int)d);
  return u.s;
}
static __device__ inline float sum16(const f32x16 v) {
  float a = ((v[0] + v[1]) + (v[2] + v[3])) + ((v[4] + v[5]) + (v[6] + v[7]));
  float b = ((v[8] + v[9]) + (v[10] + v[11])) + ((v[12] + v[13]) + (v[14] + v[15]));
  return a + b;
}

// ---------------------------------------------------------------------------
// Kernel 1 (prep0): blocks [0,1024): sr_w -> Wf fragment layout.
// Blocks [1024,1040): WK2/WV2 (stored B-fragment-linear).  Block 1040: u, bp2.
__global__ __launch_bounds__(256) void prep0(
    const float* __restrict__ sr_w, const float* __restrict__ Wq,
    const float* __restrict__ Wkv, const float* __restrict__ bq,
    const float* __restrict__ Wp, const float* __restrict__ bkv,
    const float* __restrict__ bp, ushort_t* __restrict__ Wf,
    ushort_t* __restrict__ W2f, float* __restrict__ u,
    float* __restrict__ bp2) {
  const int bid = blockIdx.x;
  const int t = threadIdx.x;
  const float SC = 0.125f * 1.4426950408889634f;
  if (bid < 1024) {
    int idx = bid * 256 + t;      // 262144
    int o = idx >> 12;
    int r = idx & 4095;
    int c = r >> 6;
    int ki = (r >> 3) & 7;
    int kj = r & 7;
    int oh = o >> 5;
    int l = ((c >> 3) & 1) * 32 + (o & 31);
    int kk = kj * 4 + (c >> 4);
    int e = c & 7;
    Wf[(ki * 2 + oh) * 16384 + kk * 512 + l * 8 + e] = f2bf(sr_w[idx]);
  } else if (bid < 1040) {
    const int eb = bid - 1024;
#pragma unroll
    for (int q = 0; q < 2; ++q) {
      int oidx = eb * 512 + t * 2 + q;   // [0,8192)
      int mat = oidx >> 12;
      int rem = oidx & 4095;
      int d = rem >> 6;
      int c = rem & 63;
      float s = 0.f;
      if (mat == 0) {
        const float* wk = Wkv + d * 128;
        const float* wq = Wq + c * 64;
#pragma unroll 16
        for (int e = 0; e < 64; ++e) s += wk[e] * wq[e];
        s *= SC;
      } else {
        const float* wk = Wkv + d * 128 + 64;
#pragma unroll 16
        for (int e = 0; e < 64; ++e) s += wk[e] * Wp[e * 64 + c];
      }
      // B-frag layout: chunk((mat*2 + c>>5)*4 + d>>4), l=((d>>3)&1)*32+(c&31)
      W2f[((mat * 2 + (c >> 5)) * 4 + (d >> 4)) * 512 +
          (((d >> 3) & 1) * 32 + (c & 31)) * 8 + (d & 7)] = f2bf(s);
    }
  } else {
    if (t < 64) {
      float s = 0.f;
      const float* wk = Wkv + t * 128;
#pragma unroll 16
      for (int e = 0; e < 64; ++e) s += wk[e] * bq[e];
      u[t] = s * SC;
    } else if (t < 128) {
      int c = t - 64;
      float s = bp[c];
#pragma unroll 16
      for (int e = 0; e < 64; ++e) s += bkv[64 + e] * Wp[e * 64 + c];
      bp2[c] = s;
    }
  }
}

// ---------------------------------------------------------------------------
// Kernel A: conv partial GEMM (unchanged).
__global__ __launch_bounds__(128) void conv_mfma(
    const float* __restrict__ x, const ushort_t* __restrict__ Wf,
    float* __restrict__ part) {
  const int t = threadIdx.x;
  const int bi = blockIdx.x;
  const int b = bi >> 6;
  const int pg = (bi >> 3) & 7;
  const int ki = bi & 7;
  const int oh = t >> 6;
  const int lane = t & 63;
  const int lo5 = lane & 31;
  const int hi = lane >> 5;

  const int P = pg * 32 + lo5;
  const int prow = P >> 4, pcol = P & 15;
  const float* rowbase =
      x + ((size_t)b * N + (prow * 8 + ki) * HW + pcol * 8) * C;
  const ushort_t* wbase = Wf + (ki * 2 + oh) * 16384 + lane * 8;

  f32x16 acc;
#pragma unroll
  for (int r = 0; r < 16; ++r) acc[r] = 0.f;

#pragma unroll
  for (int kk = 0; kk < 32; ++kk) {
    const int kj = kk >> 2;
    const int c0 = (kk & 3) * 16 + hi * 8;
    const float4* xp = reinterpret_cast<const float4*>(rowbase + kj * C + c0);
    float4 f0 = xp[0];
    float4 f1 = xp[1];
    short8v bfr = mk8(cvtpk(f0.x, f0.y), cvtpk(f0.z, f0.w), cvtpk(f1.x, f1.y),
                      cvtpk(f1.z, f1.w));
    short8v afr = *reinterpret_cast<const short8v*>(wbase + kk * 512);
    acc = __builtin_amdgcn_mfma_f32_32x32x16_bf16(afr, bfr, acc, 0, 0, 0);
  }

  float* dst = part + (size_t)bi * 2048 + oh * 1024 + lane * 16;
#pragma unroll
  for (int q = 0; q < 4; ++q) {
    *reinterpret_cast<float4*>(dst + 4 * q) =
        make_float4(acc[4 * q + 0], acc[4 * q + 1], acc[4 * q + 2],
                    acc[4 * q + 3]);
  }
}

// ---------------------------------------------------------------------------
// Kernel L: sum ki-partials + bias + LayerNorm + MT/Vp/sb directly (unchanged).
__global__ __launch_bounds__(256) void ln_prep(
    const float* __restrict__ part, const float* __restrict__ sr_b,
    const float* __restrict__ ln_g, const float* __restrict__ ln_b,
    const ushort_t* __restrict__ W2f, const float* __restrict__ u,
    ushort_t* __restrict__ MTf, ushort_t* __restrict__ VpTf,
    ushort_t* __restrict__ sbf) {
  __shared__ float convs[32 * 68];
  __shared__ float ns[32 * 68];

  const int t = threadIdx.x;
  const int b = blockIdx.x >> 3;
  const int pg = blockIdx.x & 7;
  const size_t obase = (size_t)b * 16384;

  // ---- Phase A: sum 8 ki partials + conv bias ----
  {
    const int lane = t & 63;
    const int rhalf = (t >> 6) & 1;
    const int oh = t >> 7;
    float a[8];
#pragma unroll
    for (int r = 0; r < 8; ++r) a[r] = 0.f;
#pragma unroll
    for (int ki = 0; ki < 8; ++ki) {
      const float* src = part + ((size_t)(b * 64 + pg * 8 + ki)) * 2048 +
                         oh * 1024 + lane * 16 + rhalf * 8;
      float4 u0 = *reinterpret_cast<const float4*>(src + 0);
      float4 u1 = *reinterpret_cast<const float4*>(src + 4);
      a[0] += u0.x; a[1] += u0.y; a[2] += u0.z; a[3] += u0.w;
      a[4] += u1.x; a[5] += u1.y; a[6] += u1.z; a[7] += u1.w;
    }
    const int p = lane & 31;
#pragma unroll
    for (int r = 0; r < 8; ++r) {
      int reg = rhalf * 8 + r;
      int o = oh * 32 + (reg & 3) + 8 * (reg >> 2) + 4 * (lane >> 5);
      convs[p * 68 + o] = a[r] + sr_b[o];
    }
  }
  __syncthreads();
  // ---- Phase B: LayerNorm ----
  {
    const int lane = t & 63;
    const int w = t >> 6;
    float g = ln_g[lane], bb = ln_b[lane];
#pragma unroll
    for (int rr = 0; rr < 8; ++rr) {
      int p = w * 8 + rr;
      float v = convs[p * 68 + lane];
      float s = v, s2 = v * v;
#pragma unroll
      for (int mask = 1; mask < 64; mask <<= 1) {
        s += __shfl_xor(s, mask, 64);
        s2 += __shfl_xor(s2, mask, 64);
      }
      float mu = s * (1.f / 64.f);
      float var = s2 * (1.f / 64.f) - mu * mu;
      ns[p * 68 + lane] = (v - mu) * rsqrtf(var + 1e-5f) * g + bb;
    }
  }
  __syncthreads();
  // ---- Phase C: per-wave 32x32 GEMM tile ----
  {
    const int w = t >> 6;
    const int lane = t & 63;
    const int lo5 = lane & 31;
    const int hi = lane >> 5;
    const int mat = w >> 1;     // 0 = MT, 1 = Vp
    const int n0 = w & 1;       // column half

    f32x16 acc;
#pragma unroll
    for (int r = 0; r < 16; ++r) acc[r] = 0.f;
#pragma unroll
    for (int ks = 0; ks < 4; ++ks) {
      float4 f0 = *reinterpret_cast<const float4*>(&ns[lo5 * 68 + ks * 16 + hi * 8]);
      float4 f1 = *reinterpret_cast<const float4*>(&ns[lo5 * 68 + ks * 16 + hi * 8 + 4]);
      short8v A = mk8(cvtpk(f0.x, f0.y), cvtpk(f0.z, f0.w), cvtpk(f1.x, f1.y),
                      cvtpk(f1.z, f1.w));
      short8v Bw = *reinterpret_cast<const short8v*>(
          W2f + ((mat * 2 + n0) * 4 + ks) * 512 + lane * 8);
      acc = __builtin_amdgcn_mfma_f32_32x32x16_bf16(A, Bw, acc, 0, 0, 0);
    }
    const int c = n0 * 32 + lo5;
    if (mat == 0) {
#pragma unroll
      for (int r = 0; r < 16; ++r) {
        int jl = (r & 3) + 8 * (r >> 2) + 4 * hi;
        MTf[obase + (pg * 4 + (c >> 4)) * 512 +
            (((c >> 3) & 1) * 32 + jl) * 8 + (c & 7)] = f2bf(acc[r]);
      }
    } else {
#pragma unroll
      for (int r = 0; r < 16; ++r) {
        int jg = pg * 32 + (r & 3) + 8 * (r >> 2) + 4 * hi;
        VpTf[obase + (n0 * 16 + (jg >> 4)) * 512 +
             (((jg >> 3) & 1) * 32 + (c & 31)) * 8 + (jg & 7)] = f2bf(acc[r]);
      }
    }
    // ---- sb[j] = ns[j] . u ----
    if (w == 0) {
      float s = 0.f;
      const float* ub = u + hi * 32;
#pragma unroll 8
      for (int dd = 0; dd < 32; ++dd) s += ns[lo5 * 68 + hi * 32 + dd] * ub[dd];
      s += __shfl_xor(s, 32, 64);
      if (hi == 0) sbf[b * NK + pg * 32 + lo5] = f2bf(s);
    }
  }
}

// ---------------------------------------------------------------------------
// Kernel B (R11): fused attention, MT-only LDS staging (33KB), VpT global.
// Grid 1024 = b(8) x qb(128); 256 thr = 4 waves; block = 128 queries;
// 4 blocks/CU = 16 waves/CU = 4 waves/SIMD, 4 independent blocks per CU.
__global__ __launch_bounds__(256, 4) void attn_mfma(
    const float* __restrict__ x, const ushort_t* __restrict__ MTf,
    const ushort_t* __restrict__ VpTf, const ushort_t* __restrict__ sbf,
    const float* __restrict__ bp2, float* __restrict__ outp) {
  __shared__ ushort_t sMT[16384];
  __shared__ ushort_t sSB[256];

  const int t = threadIdx.x;
  const int b = blockIdx.x >> 7;
  const int qb = blockIdx.x & 127;
  const int wave = t >> 6;
  const int lane = t & 63;
  const int lo5 = lane & 31;
  const int hi = lane >> 5;

  // ---- issue x loads FIRST (latency hides under staging + barrier) ----
  const int row = qb * 128 + wave * 32 + lo5;
  const float4* xp =
      reinterpret_cast<const float4*>(x + ((size_t)b * N + row) * 64);
  float4 xf[8];
#pragma unroll
  for (int ks = 0; ks < 4; ++ks) {
    xf[2 * ks + 0] = xp[ks * 4 + hi * 2 + 0];
    xf[2 * ks + 1] = xp[ks * 4 + hi * 2 + 1];
  }

  // ---- cooperative staging: MT + sb (256 threads, 32KB) ----
  {
    const uint4* gm = reinterpret_cast<const uint4*>(MTf + (size_t)b * 16384);
    uint4* dm = reinterpret_cast<uint4*>(sMT);
#pragma unroll
    for (int i = 0; i < 8; ++i) dm[t + i * 256] = gm[t + i * 256];
    if (t < 32)
      reinterpret_cast<uint4*>(sSB)[t] =
          reinterpret_cast<const uint4*>(sbf + b * NK)[t];
  }
  __syncthreads();

  // ---- pack X B-fragment (col=q=lane&31, k=c=ks*16+hi*8+e) ----
  short8v bx[4];
#pragma unroll
  for (int ks = 0; ks < 4; ++ks) {
    bx[ks] = mk8(cvtpk(xf[2 * ks].x, xf[2 * ks].y),
                 cvtpk(xf[2 * ks].z, xf[2 * ks].w),
                 cvtpk(xf[2 * ks + 1].x, xf[2 * ks + 1].y),
                 cvtpk(xf[2 * ks + 1].z, xf[2 * ks + 1].w));
  }

  const ushort_t* vt = VpTf + (size_t)b * 16384 + lane * 8;

  f32x16 o[2];
#pragma unroll
  for (int ct = 0; ct < 2; ++ct)
#pragma unroll
    for (int r = 0; r < 16; ++r) o[ct][r] = 0.f;
  float sum = 0.f;

#pragma unroll 2
  for (int kt = 0; kt < 8; ++kt) {
    // ---- QK^T for this 32-key tile ----
    f32x16 a0;
#pragma unroll
    for (int r = 0; r < 16; ++r) a0[r] = 0.f;
#pragma unroll
    for (int ks = 0; ks < 4; ++ks) {
      const short8v a =
          *reinterpret_cast<const short8v*>(&sMT[(kt * 4 + ks) * 512 + lane * 8]);
      a0 = __builtin_amdgcn_mfma_f32_32x32x16_bf16(a, bx[ks], a0, 0, 0, 0);
    }
    // bias k-step: adds sb[key] to every query column
    {
      ushort_t sv = sSB[kt * 32 + lo5];
      short8v a5 = mk8(hi ? 0u : (uint_t)sv, 0u, 0u, 0u);
      short8v b5 = mk8(hi ? 0u : 0x3F80u, 0u, 0u, 0u);
      a0 = __builtin_amdgcn_mfma_f32_32x32x16_bf16(a5, b5, a0, 0, 0, 0);
    }
    // ---- exp2 (no max-shift: logits small for this problem's scaling) ----
#pragma unroll
    for (int r = 0; r < 16; ++r) a0[r] = exp2f(a0[r]);
    sum += sum16(a0);
    // ---- pack P, accumulate PV (VpT fragments from global, L2-hot) ----
#pragma unroll
    for (int h = 0; h < 2; ++h) {
      const int m0 = 2 * h;
      uint_t Aw = cvtpk(a0[4 * m0 + 0], a0[4 * m0 + 1]);
      uint_t Bw = cvtpk(a0[4 * m0 + 2], a0[4 * m0 + 3]);
      uint_t Cw = cvtpk(a0[4 * m0 + 4], a0[4 * m0 + 5]);
      uint_t Dw = cvtpk(a0[4 * m0 + 6], a0[4 * m0 + 7]);
      asm volatile("v_permlane32_swap_b32 %0, %1" : "+v"(Aw), "+v"(Cw));
      asm volatile("v_permlane32_swap_b32 %0, %1" : "+v"(Bw), "+v"(Dw));
      const short8v pb = mk8(Aw, Bw, Cw, Dw);
#pragma unroll
      for (int ct = 0; ct < 2; ++ct) {
        const short8v va = *reinterpret_cast<const short8v*>(
            vt + (ct * 16 + kt * 2 + h) * 512);
        o[ct] = __builtin_amdgcn_mfma_f32_32x32x16_bf16(va, pb, o[ct], 0, 0, 0);
      }
    }
  }

  sum += __shfl_xor(sum, 32, 64);
  const float linv = 1.f / sum;

  // ---- epilogue (bp2 = bp + bkv_V@Wp) ----
  float* orow = outp + ((size_t)b * N + row) * 64;
#pragma unroll
  for (int ct = 0; ct < 2; ++ct) {
#pragma unroll
    for (int mm = 0; mm < 4; ++mm) {
      int c0 = ct * 32 + mm * 8 + hi * 4;
      float4 bpv = *reinterpret_cast<const float4*>(bp2 + c0);
      float4 r;
      r.x = o[ct][4 * mm + 0] * linv + bpv.x;
      r.y = o[ct][4 * mm + 1] * linv + bpv.y;
      r.z = o[ct][4 * mm + 2] * linv + bpv.z;
      r.w = o[ct][4 * mm + 3] * linv + bpv.w;
      *reinterpret_cast<float4*>(orow + c0) = r;
    }
  }
}

// ---------------------------------------------------------------------------
extern "C" void kernel_launch(void* const* d_in, const int* in_sizes, int n_in,
                              void* d_out, int out_size, void* d_ws,
                              size_t ws_size, hipStream_t stream) {
  const float* x    = (const float*)d_in[0];
  const float* Wq   = (const float*)d_in[3];
  const float* bq   = (const float*)d_in[4];
  const float* Wkv  = (const float*)d_in[5];
  const float* bkv  = (const float*)d_in[6];
  const float* sr_w = (const float*)d_in[7];
  const float* sr_b = (const float*)d_in[8];
  const float* ln_g = (const float*)d_in[9];
  const float* ln_b = (const float*)d_in[10];
  const float* Wp   = (const float*)d_in[11];
  const float* bp   = (const float*)d_in[12];
  float* outp = (float*)d_out;

  char* ws = (char*)d_ws;
  // [0, 512K)      Wf    bf16 conv weight fragments
  // [512K, 528K)   W2f   bf16 WK2/WV2 fragments (16KB)
  // [528K, +256)   u     fp32[64]
  // [528K+256,+512) bp2  fp32[64]
  // [1M, 5M)       part  fp32 conv partials
  // [5M, 5.25M)    MTf   [5.25M, 5.5M) VpTf   [5.5M, +4K) sbf
  ushort_t* Wf   = (ushort_t*)(ws);
  ushort_t* W2f  = (ushort_t*)(ws + (512 << 10));
  float*    u    = (float*)(ws + (528 << 10));
  float*    bp2  = (float*)(ws + (528 << 10) + 256);
  float*    part = (float*)(ws + (1024 << 10));
  ushort_t* MTf  = (ushort_t*)(ws + (5120 << 10));
  ushort_t* VpTf = (ushort_t*)(ws + (5376 << 10));
  ushort_t* sbf  = (ushort_t*)(ws + (5632 << 10));

  prep0<<<1041, 256, 0, stream>>>(sr_w, Wq, Wkv, bq, Wp, bkv, bp, Wf, W2f, u, bp2);
  conv_mfma<<<512, 128, 0, stream>>>(x, Wf, part);
  ln_prep<<<64, 256, 0, stream>>>(part, sr_b, ln_g, ln_b, W2f, u, MTf, VpTf, sbf);
  attn_mfma<<<1024, 256, 0, stream>>>(x, MTf, VpTf, sbf, bp2, outp);
}